// Round 1
// baseline (635.806 us; speedup 1.0000x reference)
//
#include <hip/hip_runtime.h>

#define B_ 8
#define C_ 64
#define T_ 256
#define F_ 256
#define H_ 128
#define TF_ (T_*F_)

typedef _Float16 half_t;
typedef _Float16 half8 __attribute__((ext_vector_type(8)));
typedef float float4v __attribute__((ext_vector_type(4)));

// ---------------- Kernel 1: x [B,C,T,F] fp32 -> xt [B, T*F, C] fp16 ----------------
__global__ __launch_bounds__(256) void k_transpose(const float* __restrict__ x,
                                                   half_t* __restrict__ xt) {
    __shared__ float lds[64 * 65];
    int blk = blockIdx.x;
    int b   = blk >> 10;            // /1024
    int tf0 = (blk & 1023) << 6;    // *64
    int tid = threadIdx.x;
    int tfl   = tid & 63;
    int cbase = tid >> 6;           // 0..3
    const float* xp = x + (size_t)(b * C_) * TF_ + tf0 + tfl;
#pragma unroll
    for (int i = 0; i < 16; ++i) {
        int c = cbase + i * 4;
        lds[tfl * 65 + c] = xp[(size_t)c * TF_];
    }
    __syncthreads();
    int row = tid >> 2;             // 0..63 (tf local)
    int c0  = (tid & 3) << 4;       // 0,16,32,48
    float v[16];
#pragma unroll
    for (int k = 0; k < 16; ++k) v[k] = lds[row * 65 + c0 + k];
    half8 o0, o1;
#pragma unroll
    for (int k = 0; k < 8; ++k) { o0[k] = (half_t)v[k]; o1[k] = (half_t)v[8 + k]; }
    half_t* op = xt + ((size_t)b * TF_ + tf0 + row) * C_ + c0;
    *(half8*)op       = o0;
    *(half8*)(op + 8) = o1;
}

// ---------------- Kernel 2: fused dual GRU, MFMA 16x16x32 f16 ----------------
__device__ inline half8 load_w8(const float* __restrict__ p) {
    float4v a = *(const float4v*)p;
    float4v b = *(const float4v*)(p + 4);
    half8 r;
    r[0] = (half_t)a[0]; r[1] = (half_t)a[1]; r[2] = (half_t)a[2]; r[3] = (half_t)a[3];
    r[4] = (half_t)b[0]; r[5] = (half_t)b[1]; r[6] = (half_t)b[2]; r[7] = (half_t)b[3];
    return r;
}

#define MFMA(a, b, c) __builtin_amdgcn_mfma_f32_16x16x32_f16((a), (b), (c), 0, 0, 0)

// Block: 512 threads = 8 waves. Block handles 16 sequences of one GRU.
// Wave w owns hidden units j in [16w, 16w+16) -> N-tiles {w (r), w+8 (z), w+16 (n)}.
// A-frag: lane holds A[m=lane&15][k=quad*8+j]; B-frag: B[k=quad*8+j][n=lane&15];
// C/D: lane holds D[m=quad*4+reg][n=lane&15].
__global__ __launch_bounds__(512, 2) void k_gru(
    const half_t* __restrict__ xt,
    const float* __restrict__ Wih_t, const float* __restrict__ Whh_t,
    const float* __restrict__ bih_t, const float* __restrict__ bhh_t,
    const float* __restrict__ Wih_f, const float* __restrict__ Whh_f,
    const float* __restrict__ bih_f, const float* __restrict__ bhh_f,
    float* __restrict__ h_t_out, float* __restrict__ h_f_out) {
    __shared__ half_t hbuf[16 * 136];   // [m][k], row stride 136 (16B mult, pad)

    int tid  = threadIdx.x;
    int w    = tid >> 6;
    int lane = tid & 63;
    int nidx = lane & 15;
    int quad = lane >> 4;

    int bi  = blockIdx.x;
    bool isf = bi >= 128;
    int lbi = bi & 127;
    int b   = lbi >> 4;
    int g16 = (lbi & 15) << 4;    // f0 (time) or t0 (freq)

    const float* Wih = isf ? Wih_f : Wih_t;
    const float* Whh = isf ? Whh_f : Whh_t;
    const float* bih = isf ? bih_f : bih_t;
    const float* bhh = isf ? bhh_f : bhh_t;
    float* hout      = isf ? h_f_out : h_t_out;

    size_t Sm = isf ? (size_t)(F_ * C_) : (size_t)C_;   // stride between the 16 sequences
    size_t Ss = isf ? (size_t)C_ : (size_t)(F_ * C_);   // stride per recurrence step
    size_t abase = (size_t)b * TF_ * C_ + (size_t)g16 * Sm;

    // ---- load weight B-fragments into registers (once) ----
    int gr = w * 16 + nidx;     // r gate row  [0,128)
    int gz = gr + 128;          // z gate row
    int gn = gr + 256;          // n gate row
    int ko = quad * 8;

    half8 wir0 = load_w8(Wih + gr * 64 + ko);
    half8 wir1 = load_w8(Wih + gr * 64 + 32 + ko);
    half8 wiz0 = load_w8(Wih + gz * 64 + ko);
    half8 wiz1 = load_w8(Wih + gz * 64 + 32 + ko);
    half8 win0 = load_w8(Wih + gn * 64 + ko);
    half8 win1 = load_w8(Wih + gn * 64 + 32 + ko);
    half8 whr[4], whz[4], whn[4];
#pragma unroll
    for (int kt = 0; kt < 4; ++kt) {
        whr[kt] = load_w8(Whh + gr * 128 + kt * 32 + ko);
        whz[kt] = load_w8(Whh + gz * 128 + kt * 32 + ko);
        whn[kt] = load_w8(Whh + gn * 128 + kt * 32 + ko);
    }
    float br  = bih[gr] + bhh[gr];
    float bz  = bih[gz] + bhh[gz];
    float bin = bih[gn];
    float bhn = bhh[gn];

    // zero h buffer
    for (int idx = tid; idx < 16 * 136; idx += 512) hbuf[idx] = (half_t)0.f;
    float h_old[4] = {0.f, 0.f, 0.f, 0.f};
    __syncthreads();

    const half_t* ap = xt + abase + (size_t)nidx * Sm + ko;

    for (int t = 0; t < 256; ++t) {
        half8 xa0 = *(const half8*)ap;
        half8 xa1 = *(const half8*)(ap + 32);
        half8 ha0 = *(const half8*)&hbuf[nidx * 136 + 0  + ko];
        half8 ha1 = *(const half8*)&hbuf[nidx * 136 + 32 + ko];
        half8 ha2 = *(const half8*)&hbuf[nidx * 136 + 64 + ko];
        half8 ha3 = *(const half8*)&hbuf[nidx * 136 + 96 + ko];

        float4v ar  = {br, br, br, br};
        float4v az  = {bz, bz, bz, bz};
        float4v ain = {bin, bin, bin, bin};
        float4v ahn = {bhn, bhn, bhn, bhn};

        ar  = MFMA(xa0, wir0, ar);  ar  = MFMA(xa1, wir1, ar);
        az  = MFMA(xa0, wiz0, az);  az  = MFMA(xa1, wiz1, az);
        ain = MFMA(xa0, win0, ain); ain = MFMA(xa1, win1, ain);
#pragma unroll
        for (int kt = 0; kt < 4; ++kt) {
            half8 ha = (kt == 0) ? ha0 : (kt == 1) ? ha1 : (kt == 2) ? ha2 : ha3;
            ar  = MFMA(ha, whr[kt], ar);
            az  = MFMA(ha, whz[kt], az);
            ahn = MFMA(ha, whn[kt], ahn);
        }

        float hnew[4];
#pragma unroll
        for (int rg = 0; rg < 4; ++rg) {
            float r = 1.f / (1.f + __expf(-ar[rg]));
            float z = 1.f / (1.f + __expf(-az[rg]));
            float npre = ain[rg] + r * ahn[rg];
            float n = 1.f - 2.f / (__expf(2.f * npre) + 1.f);   // tanh
            float h = (1.f - z) * n + z * h_old[rg];
            h_old[rg] = h;
            hnew[rg] = h;
        }

        __syncthreads();   // all waves done reading h_{t-1}
#pragma unroll
        for (int rg = 0; rg < 4; ++rg) {
            hbuf[(quad * 4 + rg) * 136 + w * 16 + nidx] = (half_t)hnew[rg];
        }
        __syncthreads();   // h_t visible to all
        ap += Ss;
    }

    int srow = (b << 8) + g16;
#pragma unroll
    for (int rg = 0; rg < 4; ++rg) {
        hout[(size_t)(srow + quad * 4 + rg) * H_ + w * 16 + nidx] = h_old[rg];
    }
}

// ---------------- Kernel 3: out[b,c,t,f] = bp[c] + sum_h Wp[c,h]*(h_t[b,t,h]+h_f[b,t,h]) ----------------
__global__ __launch_bounds__(256) void k_out(const float* __restrict__ h_t,
                                             const float* __restrict__ h_f,
                                             const float* __restrict__ Wp,
                                             const float* __restrict__ bp,
                                             float* __restrict__ out) {
    __shared__ float sv[128];
    __shared__ float part[4][64];
    __shared__ float orow[64];
    int blk = blockIdx.x;
    int b = blk >> 8;
    int i = blk & 255;
    int tid = threadIdx.x;
    size_t hoff = ((size_t)(b * 256 + i)) * 128;
    if (tid < 128) sv[tid] = h_t[hoff + tid] + h_f[hoff + tid];
    __syncthreads();
    int c = tid & 63;
    int q = tid >> 6;
    float p = 0.f;
    const float* wp = Wp + c * 128 + q * 32;
#pragma unroll
    for (int k = 0; k < 32; ++k) p += wp[k] * sv[q * 32 + k];
    part[q][c] = p;
    __syncthreads();
    if (tid < 64) orow[tid] = part[0][tid] + part[1][tid] + part[2][tid] + part[3][tid] + bp[tid];
    __syncthreads();
    int oc  = tid >> 2;
    int sgm = tid & 3;
    float v = orow[oc];
    float4v vv = {v, v, v, v};
    float* op = out + (((size_t)(b * 64 + oc)) * 256 + i) * 256 + sgm * 4;
#pragma unroll
    for (int k = 0; k < 16; ++k) *(float4v*)(op + k * 16) = vv;
}

extern "C" void kernel_launch(void* const* d_in, const int* in_sizes, int n_in,
                              void* d_out, int out_size, void* d_ws, size_t ws_size,
                              hipStream_t stream) {
    const float* x     = (const float*)d_in[0];
    const float* Wih_t = (const float*)d_in[1];
    const float* Whh_t = (const float*)d_in[2];
    const float* bih_t = (const float*)d_in[3];
    const float* bhh_t = (const float*)d_in[4];
    const float* Wih_f = (const float*)d_in[5];
    const float* Whh_f = (const float*)d_in[6];
    const float* bih_f = (const float*)d_in[7];
    const float* bhh_f = (const float*)d_in[8];
    const float* Wp    = (const float*)d_in[9];
    const float* bp    = (const float*)d_in[10];
    float* out = (float*)d_out;

    // xt (fp16, 64 MiB) lives in d_out: fully consumed by k_gru before k_out
    // overwrites d_out with the final result. h_t/h_f (2 MiB) live in ws.
    half_t* xt     = (half_t*)d_out;
    float* h_t_out = (float*)((char*)d_ws);
    float* h_f_out = (float*)((char*)d_ws + (size_t)2048 * 128 * 4);

    k_transpose<<<8192, 256, 0, stream>>>(x, xt);
    k_gru<<<256, 512, 0, stream>>>(xt, Wih_t, Whh_t, bih_t, bhh_t,
                                   Wih_f, Whh_f, bih_f, bhh_f, h_t_out, h_f_out);
    k_out<<<2048, 256, 0, stream>>>(h_t_out, h_f_out, Wp, bp, out);
}

// Round 2
// 455.154 us; speedup vs baseline: 1.3969x; 1.3969x over previous
//
#include <hip/hip_runtime.h>

#define B_ 8
#define C_ 64
#define T_ 256
#define F_ 256
#define H_ 128
#define TF_ (T_*F_)

typedef _Float16 half_t;
typedef _Float16 half8 __attribute__((ext_vector_type(8)));
typedef float float4v __attribute__((ext_vector_type(4)));

#if __has_builtin(__builtin_amdgcn_exp2f)
#define EXP2F(x) __builtin_amdgcn_exp2f(x)
#else
static __device__ inline float EXP2F(float x) { float r; asm("v_exp_f32 %0, %1" : "=v"(r) : "v"(x)); return r; }
#endif
#if __has_builtin(__builtin_amdgcn_rcpf)
#define RCPF(x) __builtin_amdgcn_rcpf(x)
#else
static __device__ inline float RCPF(float x) { float r; asm("v_rcp_f32 %0, %1" : "=v"(r) : "v"(x)); return r; }
#endif

#define NEG_L2E  (-1.4426950408889634f)
#define NEG_2L2E (-2.8853900817779268f)

// ---------------- Kernel 1: x [B,C,T,F] fp32 -> xt [B, T*F, C] fp16 ----------------
__global__ __launch_bounds__(256) void k_transpose(const float* __restrict__ x,
                                                   half_t* __restrict__ xt) {
    __shared__ float lds[64 * 65];
    int blk = blockIdx.x;
    int b   = blk >> 10;            // /1024
    int tf0 = (blk & 1023) << 6;    // *64
    int tid = threadIdx.x;
    int tfl   = tid & 63;
    int cbase = tid >> 6;           // 0..3
    const float* xp = x + (size_t)(b * C_) * TF_ + tf0 + tfl;
#pragma unroll
    for (int i = 0; i < 16; ++i) {
        int c = cbase + i * 4;
        lds[tfl * 65 + c] = xp[(size_t)c * TF_];
    }
    __syncthreads();
    int row = tid >> 2;             // 0..63 (tf local)
    int c0  = (tid & 3) << 4;       // 0,16,32,48
    float v[16];
#pragma unroll
    for (int k = 0; k < 16; ++k) v[k] = lds[row * 65 + c0 + k];
    half8 o0, o1;
#pragma unroll
    for (int k = 0; k < 8; ++k) { o0[k] = (half_t)v[k]; o1[k] = (half_t)v[8 + k]; }
    half_t* op = xt + ((size_t)b * TF_ + tf0 + row) * C_ + c0;
    *(half8*)op       = o0;
    *(half8*)(op + 8) = o1;
}

// ---------------- Kernel 2: fused dual GRU, MFMA 16x16x32 f16 ----------------
__device__ inline half8 load_w8s(const float* __restrict__ p, float s) {
    half8 r;
#pragma unroll
    for (int k = 0; k < 8; ++k) r[k] = (half_t)(p[k] * s);
    return r;
}

#define MFMA(a, b, c) __builtin_amdgcn_mfma_f32_16x16x32_f16((a), (b), (c), 0, 0, 0)

// Block: 512 threads = 8 waves, M=16 sequences, wave w owns hidden units [16w,16w+16).
// A-frag: lane holds A[m=lane&15][k=quad*8+j]; B-frag: B[k=quad*8+j][n=lane&15];
// C/D: lane holds D[m=quad*4+reg][n=lane&15].
// r/z weights pre-scaled by -log2(e); n weights pre-scaled by -2*log2(e) so the
// accumulator feeds v_exp_f32 directly (sigmoid = rcp(1+exp2(acc))).
__global__ __launch_bounds__(512, 2) void k_gru(
    const half_t* __restrict__ xt,
    const float* __restrict__ Wih_t, const float* __restrict__ Whh_t,
    const float* __restrict__ bih_t, const float* __restrict__ bhh_t,
    const float* __restrict__ Wih_f, const float* __restrict__ Whh_f,
    const float* __restrict__ bih_f, const float* __restrict__ bhh_f,
    float* __restrict__ h_t_out, float* __restrict__ h_f_out) {
    __shared__ half_t hbuf0[16 * 136];   // h at even t (row stride 136 halves)
    __shared__ half_t hbuf1[16 * 136];   // h at odd t

    int tid  = threadIdx.x;
    int w    = tid >> 6;
    int lane = tid & 63;
    int nidx = lane & 15;
    int quad = lane >> 4;

    int bi  = blockIdx.x;
    bool isf = bi >= 128;
    int lbi = bi & 127;
    int b   = lbi >> 4;
    int g16 = (lbi & 15) << 4;    // f0 (time) or t0 (freq)

    const float* Wih = isf ? Wih_f : Wih_t;
    const float* Whh = isf ? Whh_f : Whh_t;
    const float* bih = isf ? bih_f : bih_t;
    const float* bhh = isf ? bhh_f : bhh_t;
    float* hout      = isf ? h_f_out : h_t_out;

    size_t Sm = isf ? (size_t)(F_ * C_) : (size_t)C_;   // stride between the 16 sequences
    size_t Ss = isf ? (size_t)C_ : (size_t)(F_ * C_);   // stride per recurrence step
    size_t abase = (size_t)b * TF_ * C_ + (size_t)g16 * Sm;

    // ---- weight B-fragments in registers (loaded once, pre-scaled) ----
    int gr = w * 16 + nidx;     // r gate row  [0,128)
    int gz = gr + 128;          // z gate row
    int gn = gr + 256;          // n gate row
    int ko = quad * 8;

    half8 wir0 = load_w8s(Wih + gr * 64 + ko,      NEG_L2E);
    half8 wir1 = load_w8s(Wih + gr * 64 + 32 + ko, NEG_L2E);
    half8 wiz0 = load_w8s(Wih + gz * 64 + ko,      NEG_L2E);
    half8 wiz1 = load_w8s(Wih + gz * 64 + 32 + ko, NEG_L2E);
    half8 win0 = load_w8s(Wih + gn * 64 + ko,      NEG_2L2E);
    half8 win1 = load_w8s(Wih + gn * 64 + 32 + ko, NEG_2L2E);
    half8 whr[4], whz[4], whn[4];
#pragma unroll
    for (int kt = 0; kt < 4; ++kt) {
        whr[kt] = load_w8s(Whh + gr * 128 + kt * 32 + ko, NEG_L2E);
        whz[kt] = load_w8s(Whh + gz * 128 + kt * 32 + ko, NEG_L2E);
        whn[kt] = load_w8s(Whh + gn * 128 + kt * 32 + ko, NEG_2L2E);
    }
    float br  = NEG_L2E  * (bih[gr] + bhh[gr]);
    float bz  = NEG_L2E  * (bih[gz] + bhh[gz]);
    float bin = NEG_2L2E * bih[gn];
    float bhn = NEG_2L2E * bhh[gn];

    for (int idx = tid; idx < 16 * 136; idx += 512) hbuf0[idx] = (half_t)0.f;
    float h_old[4] = {0.f, 0.f, 0.f, 0.f};
    __syncthreads();

    const half_t* ap = xt + abase + (size_t)nidx * Sm + ko;
    half8 xaA0 = *(const half8*)ap;
    half8 xaA1 = *(const half8*)(ap + 32);
    ap += Ss;
    half8 xaB0, xaB1;

#define GRU_STEP(XA0, XA1, RBUF, WBUF)                                          \
    {                                                                           \
        const half_t* hrow = (RBUF) + nidx * 136 + ko;                          \
        half8 ha0 = *(const half8*)(hrow);                                      \
        half8 ha1 = *(const half8*)(hrow + 32);                                 \
        half8 ha2 = *(const half8*)(hrow + 64);                                 \
        half8 ha3 = *(const half8*)(hrow + 96);                                 \
        float4v ar  = {br, br, br, br};                                         \
        float4v az  = {bz, bz, bz, bz};                                         \
        float4v ain = {bin, bin, bin, bin};                                     \
        float4v ahn = {bhn, bhn, bhn, bhn};                                     \
        ar  = MFMA(XA0, wir0, ar);  ar  = MFMA(XA1, wir1, ar);                  \
        az  = MFMA(XA0, wiz0, az);  az  = MFMA(XA1, wiz1, az);                  \
        ain = MFMA(XA0, win0, ain); ain = MFMA(XA1, win1, ain);                 \
        ar  = MFMA(ha0, whr[0], ar);  ar  = MFMA(ha1, whr[1], ar);              \
        ar  = MFMA(ha2, whr[2], ar);  ar  = MFMA(ha3, whr[3], ar);              \
        az  = MFMA(ha0, whz[0], az);  az  = MFMA(ha1, whz[1], az);              \
        az  = MFMA(ha2, whz[2], az);  az  = MFMA(ha3, whz[3], az);              \
        ahn = MFMA(ha0, whn[0], ahn); ahn = MFMA(ha1, whn[1], ahn);             \
        ahn = MFMA(ha2, whn[2], ahn); ahn = MFMA(ha3, whn[3], ahn);             \
        _Pragma("unroll")                                                       \
        for (int rg = 0; rg < 4; ++rg) {                                        \
            float r  = RCPF(1.f + EXP2F(ar[rg]));                               \
            float z  = RCPF(1.f + EXP2F(az[rg]));                               \
            float np = ain[rg] + r * ahn[rg];    /* scaled by -2*log2e */       \
            float n  = 2.f * RCPF(1.f + EXP2F(np)) - 1.f;                       \
            float h  = n + z * (h_old[rg] - n);                                 \
            h_old[rg] = h;                                                      \
            (WBUF)[(quad * 4 + rg) * 136 + w * 16 + nidx] = (half_t)h;          \
        }                                                                       \
        __syncthreads();                                                        \
    }

    for (int it = 0; it < 128; ++it) {
        // prefetch x for t=2*it+1, then step t=2*it (reads hbuf0, writes hbuf1)
        xaB0 = *(const half8*)ap;
        xaB1 = *(const half8*)(ap + 32);
        ap += Ss;
        GRU_STEP(xaA0, xaA1, hbuf0, hbuf1)
        // prefetch x for t=2*it+2 (last iter reads past xt: stays inside d_out, unused)
        xaA0 = *(const half8*)ap;
        xaA1 = *(const half8*)(ap + 32);
        ap += Ss;
        GRU_STEP(xaB0, xaB1, hbuf1, hbuf0)
    }
#undef GRU_STEP

    int srow = (b << 8) + g16;
#pragma unroll
    for (int rg = 0; rg < 4; ++rg) {
        hout[(size_t)(srow + quad * 4 + rg) * H_ + w * 16 + nidx] = h_old[rg];
    }
}

// ---------------- Kernel 3: out[b,c,t,f] = bp[c] + sum_h Wp[c,h]*(h_t[b,t,h]+h_f[b,t,h]) ----------------
__global__ __launch_bounds__(256) void k_out(const float* __restrict__ h_t,
                                             const float* __restrict__ h_f,
                                             const float* __restrict__ Wp,
                                             const float* __restrict__ bp,
                                             float* __restrict__ out) {
    __shared__ float sv[128];
    __shared__ float part[4][64];
    __shared__ float orow[64];
    int blk = blockIdx.x;
    int b = blk >> 8;
    int i = blk & 255;              // t index
    int tid = threadIdx.x;
    size_t hoff = ((size_t)(b * 256 + i)) * 128;
    if (tid < 128) sv[tid] = h_t[hoff + tid] + h_f[hoff + tid];
    __syncthreads();
    int c = tid & 63;
    int q = tid >> 6;
    float p = 0.f;
    const float* wp = Wp + c * 128 + q * 32;
#pragma unroll
    for (int k = 0; k < 32; ++k) p += wp[k] * sv[q * 32 + k];
    part[q][c] = p;
    __syncthreads();
    if (tid < 64) orow[tid] = part[0][tid] + part[1][tid] + part[2][tid] + part[3][tid] + bp[tid];
    __syncthreads();
    // write: wave wv writes full contiguous rows out[b, c, i, 0:256] (1 KB each)
    int wv   = tid >> 6;
    int lane = tid & 63;
#pragma unroll
    for (int itr = 0; itr < 16; ++itr) {
        int cc = itr * 4 + wv;
        float v = orow[cc];
        float4v vv = {v, v, v, v};
        *(float4v*)(out + (((size_t)(b * 64 + cc)) * 256 + i) * 256 + lane * 4) = vv;
    }
}

extern "C" void kernel_launch(void* const* d_in, const int* in_sizes, int n_in,
                              void* d_out, int out_size, void* d_ws, size_t ws_size,
                              hipStream_t stream) {
    const float* x     = (const float*)d_in[0];
    const float* Wih_t = (const float*)d_in[1];
    const float* Whh_t = (const float*)d_in[2];
    const float* bih_t = (const float*)d_in[3];
    const float* bhh_t = (const float*)d_in[4];
    const float* Wih_f = (const float*)d_in[5];
    const float* Whh_f = (const float*)d_in[6];
    const float* bih_f = (const float*)d_in[7];
    const float* bhh_f = (const float*)d_in[8];
    const float* Wp    = (const float*)d_in[9];
    const float* bp    = (const float*)d_in[10];
    float* out = (float*)d_out;

    // xt (fp16, 64 MiB) lives in d_out: fully consumed by k_gru before k_out
    // overwrites d_out with the final result. h_t/h_f (2 MiB) live in ws.
    half_t* xt     = (half_t*)d_out;
    float* h_t_out = (float*)((char*)d_ws);
    float* h_f_out = (float*)((char*)d_ws + (size_t)2048 * 128 * 4);

    k_transpose<<<8192, 256, 0, stream>>>(x, xt);
    k_gru<<<256, 512, 0, stream>>>(xt, Wih_t, Whh_t, bih_t, bhh_t,
                                   Wih_f, Whh_f, bih_f, bhh_f, h_t_out, h_f_out);
    k_out<<<2048, 256, 0, stream>>>(h_t_out, h_f_out, Wp, bp, out);
}